// Round 6
// baseline (39.792 us; speedup 1.0000x reference)
//
#include <hip/hip_runtime.h>

#define NB 16
#define NA 3
#define NC 80
#define NH 76
#define NW 76
#define MAX_GT 50
#define PLANE (NH * NW)       // 5776
#define CH (5 + NC)           // 85
#define IMG 608.0f
#define SIL 0.6f
#define OBJSC 5.0f
#define BLOCK 256
#define BPP ((PLANE + BLOCK - 1) / BLOCK)   // 23
#define GRID (NB * NA * BPP)                // 1104

// ws layout (float/int slots)
#define CNT_OFF 0                    // [0]: finished-block counter (int)
#define NV_OFF 16                    // nv[NB], cnt[NB] (ints)
#define GT_OFF 64                    // NB*MAX_GT*8 floats: xlo,xhi,ylo,yhi,gw,gh,area,pad
#define ENT_OFF (GT_OFF + NB * MAX_GT * 8)   // NB*MAX_GT*8: key,tx,ty,tw,th,tconf,cls,pad
#define PART_OFF (ENT_OFF + NB * MAX_GT * 8) // GRID partials

__device__ __constant__ float c_aw[3] = {1.5f, 2.375f, 5.0f};
__device__ __constant__ float c_ah[3] = {2.0f, 4.5f, 3.5f};

__device__ inline float fast_sigmoid(float v) {
    return __builtin_amdgcn_rcpf(1.f + __expf(-v));
}

__device__ inline float iou_full(float x1, float y1, float w1, float h1,
                                 float x2, float y2, float w2, float h2) {
    float mx = fminf(x1 - w1 * 0.5f, x2 - w2 * 0.5f);
    float Mx = fmaxf(x1 + w1 * 0.5f, x2 + w2 * 0.5f);
    float my = fminf(y1 - h1 * 0.5f, y2 - h2 * 0.5f);
    float My = fmaxf(y1 + h1 * 0.5f, y2 + h2 * 0.5f);
    float cw = w1 + w2 - (Mx - mx);
    float ch = h1 + h2 - (My - my);
    float carea = (cw <= 0.f || ch <= 0.f) ? 0.f : cw * ch;
    float uarea = w1 * h1 + w2 * h2 - carea;
    return carea / uarea;
}

// Pass A (16 blocks x 64): GT transform + parallel last-write-wins dedup.
// Writes GT boxes, compact entries, nv/cnt to ws; resets the finish counter.
__global__ void yolo_prep(const float* __restrict__ out,
                          const float* __restrict__ target,
                          float* __restrict__ ws) {
    int b = blockIdx.x;
    int t = threadIdx.x;
    __shared__ int s_key[64];
    __shared__ float s_val[MAX_GT][8];
    __shared__ int s_cnt;

    if (t == 0) s_cnt = 0;
    if (b == 0 && t == 0) ((int*)ws)[CNT_OFF] = 0;   // reset for last-block logic

    float pxr = 1.f;
    int key = -1;
    float e_tx = 0.f, e_ty = 0.f, e_tw = 0.f, e_th = 0.f, e_tc = 0.f, e_cls = 0.f;

    if (t < MAX_GT) {
        const float* tg = target + (size_t)b * MAX_GT * 5 + t * 5;
        float gcls = tg[0];
        pxr = tg[1];
        float gx = tg[1] * (float)NW / IMG;
        float gy = tg[2] * (float)NH / IMG;
        float gw = tg[3] * (float)NW / IMG;
        float gh = tg[4] * (float)NH / IMG;

        float* gt = ws + GT_OFF + ((size_t)b * MAX_GT + t) * 8;
        gt[0] = gx - 0.5f * gw;
        gt[1] = gx + 0.5f * gw;
        gt[2] = gy - 0.5f * gh;
        gt[3] = gy + 0.5f * gh;
        gt[4] = gw;
        gt[5] = gh;
        gt[6] = gw * gh;
        gt[7] = 0.f;

        int bn = 0; float best = -1.f;
        #pragma unroll
        for (int aa = 0; aa < NA; aa++) {
            float ca = fminf(gw, c_aw[aa]) * fminf(gh, c_ah[aa]);
            float ua = gw * gh + c_aw[aa] * c_ah[aa] - ca;
            float v = ca / ua;
            if (v > best) { best = v; bn = aa; }
        }
        int gi = (int)gx, gj = (int)gy;
        int gic = min(max(gi, 0), NW - 1), gjc = min(max(gj, 0), NH - 1);

        const float* pb = out + (((size_t)b * NA + bn) * CH) * PLANE
                          + (size_t)gjc * NW + gic;
        float q0 = pb[0];
        float q1 = pb[PLANE];
        float q2 = pb[2 * (size_t)PLANE];
        float q3 = pb[3 * (size_t)PLANE];
        float ppx = fast_sigmoid(q0) + (float)gic;
        float ppy = fast_sigmoid(q1) + (float)gjc;
        float ppw = __expf(q2) * c_aw[bn];
        float pph = __expf(q3) * c_ah[bn];
        float iou = iou_full(gx, gy, gw, gh, ppx, ppy, ppw, pph);

        key = (gi >= 0 && gi < NW && gj >= 0 && gj < NH)
                  ? ((bn * NH + gj) * NW + gi) : -1;
        e_tx = gx - (float)gi;
        e_ty = gy - (float)gj;
        e_tw = __logf(gw / c_aw[bn]);
        e_th = __logf(gh / c_ah[bn]);
        e_tc = iou;
        e_cls = gcls;
    }
    s_key[t] = key;
    unsigned long long zm = __ballot((t < MAX_GT) && (pxr == 0.f));
    int nv = zm ? (int)(__ffsll((long long)zm) - 1) : MAX_GT;
    __syncthreads();

    bool winner = (t < nv) && (key >= 0);
    if (winner) {
        for (int u = t + 1; u < nv; u++)
            if (s_key[u] == key) { winner = false; break; }
    }
    if (winner) {
        int slot = atomicAdd(&s_cnt, 1);
        float* ent = ws + ENT_OFF + ((size_t)b * MAX_GT + slot) * 8;
        ent[0] = (float)key;   // < 2^24, exact in float
        ent[1] = e_tx;
        ent[2] = e_ty;
        ent[3] = e_tw;
        ent[4] = e_th;
        ent[5] = e_tc;
        ent[6] = e_cls;
        ent[7] = 0.f;
    }
    __syncthreads();
    if (t == 0) {
        ((int*)ws)[NV_OFF + b] = nv;
        ((int*)ws)[NV_OFF + NB + b] = s_cnt;
    }
}

// Pass B: dense per-cell loss; coalesced L2 read of prep data; CE wave-coop;
// per-block partial store; LAST block reduces all partials -> d_out.
__global__ __launch_bounds__(BLOCK) void yolo_main(const float* __restrict__ out,
                                                   float* __restrict__ ws,
                                                   float* __restrict__ d_out) {
    const int bid = blockIdx.x;
    const int plane_id = bid / BPP;
    const int cb = bid % BPP;
    const int b = plane_id / NA;
    const int a = plane_id % NA;
    const int t = threadIdx.x;
    const int cell = cb * BLOCK + t;
    const bool incell = (cell < PLANE);

    __shared__ float s_gt[MAX_GT][8];
    __shared__ float s_ent[MAX_GT][8];
    __shared__ int s_ovr[BLOCK];
    __shared__ int s_ce_cell[MAX_GT];
    __shared__ int s_ce_cls[MAX_GT];
    __shared__ int s_nv, s_cnt, s_nce, s_last;
    __shared__ float s_red[BLOCK / 64];

    // dense channel loads issued first (hide under LDS fill)
    const float* base = out + ((size_t)(b * NA + a) * CH) * PLANE + cell;
    float o0 = 0.f, o1 = 0.f, o2 = 0.f, o3 = 0.f, o4 = 0.f;
    if (incell) {
        o0 = base[0];
        o1 = base[PLANE];
        o2 = base[2 * (size_t)PLANE];
        o3 = base[3 * (size_t)PLANE];
        o4 = base[4 * (size_t)PLANE];
    }

    s_ovr[t] = -1;
    if (t == 0) {
        s_nce = 0;
        s_nv = ((const int*)ws)[NV_OFF + b];
        s_cnt = ((const int*)ws)[NV_OFF + NB + b];
    }
    // coalesced L2 loads of prep data (400 floats each)
    {
        const float* gt = ws + GT_OFF + (size_t)b * MAX_GT * 8;
        const float* ent = ws + ENT_OFF + (size_t)b * MAX_GT * 8;
        for (int i = t; i < MAX_GT * 8; i += BLOCK) {
            ((float*)s_gt)[i] = gt[i];
            ((float*)s_ent)[i] = ent[i];
        }
    }
    __syncthreads();

    // scatter entries into this block's per-cell override map
    if (t < s_cnt) {
        int k = (int)s_ent[t][0];
        int ae = k / PLANE;
        int local = (k - ae * PLANE) - cb * BLOCK;
        if (ae == a && local >= 0 && local < BLOCK) s_ovr[local] = t;
    }
    __syncthreads();

    float loss = 0.f;
    if (incell) {
        int j = cell / NW, i = cell - (cell / NW) * NW;
        float x = fast_sigmoid(o0), y = fast_sigmoid(o1), conf = fast_sigmoid(o4);
        float pw = __expf(o2) * c_aw[a], ph = __expf(o3) * c_ah[a];
        float px = x + (float)i, py = y + (float)j;
        float pxlo = px - 0.5f * pw, pxhi = px + 0.5f * pw;
        float pylo = py - 0.5f * ph, pyhi = py + 0.5f * ph;
        float pa = pw * ph;

        bool silent = false;
        int nv = s_nv;
        #pragma unroll 2
        for (int tt = 0; tt < nv; tt++) {
            float4 gA = *(const float4*)&s_gt[tt][0];   // xlo,xhi,ylo,yhi
            float4 gB = *(const float4*)&s_gt[tt][4];   // gw,gh,area,pad
            float mx = fminf(pxlo, gA.x), Mx = fmaxf(pxhi, gA.y);
            float my = fminf(pylo, gA.z), My = fmaxf(pyhi, gA.w);
            float cw = pw + gB.x - (Mx - mx);
            float chh = ph + gB.y - (My - my);
            float ca = cw * chh;
            float ua = pa + gB.z - ca;
            silent |= ((cw > 0.f) & (chh > 0.f) & (ca > SIL * ua));
        }
        float cm2 = silent ? 0.f : 1.f;   // NOOBJ_SCALE = 1

        float tx = 0.5f, ty = 0.5f, tw = 0.f, th = 0.f, tconf = 0.f;
        int ov = s_ovr[t];
        if (ov >= 0) {
            tx = s_ent[ov][1];
            ty = s_ent[ov][2];
            tw = s_ent[ov][3];
            th = s_ent[ov][4];
            tconf = s_ent[ov][5];
            cm2 = OBJSC;
            int idx = atomicAdd(&s_nce, 1);
            s_ce_cell[idx] = cell;
            s_ce_cls[idx] = (int)s_ent[ov][6];
        }

        float dx = x - tx, dy = y - ty, dw = o2 - tw, dh = o3 - th, dc = conf - tconf;
        loss = 0.5f * (dx * dx + dy * dy + dw * dw + dh * dh + cm2 * dc * dc);
    }
    __syncthreads();

    // wave-cooperative CE for this block's GT cells
    int nce = s_nce;
    int wid = t >> 6, lane = t & 63;
    for (int k = wid; k < nce; k += BLOCK / 64) {
        int ccell = s_ce_cell[k];
        int ccls = s_ce_cls[k];
        const float* cb0 = out + ((size_t)(b * NA + a) * CH + 5) * PLANE + ccell;
        float v1 = cb0[(size_t)lane * PLANE];
        float v2 = (lane < NC - 64) ? cb0[(size_t)(lane + 64) * PLANE] : -3.4e38f;
        float m = fmaxf(v1, v2);
        #pragma unroll
        for (int off = 32; off; off >>= 1) m = fmaxf(m, __shfl_xor(m, off));
        float e = __expf(v1 - m) + ((lane < NC - 64) ? __expf(v2 - m) : 0.f);
        #pragma unroll
        for (int off = 32; off; off >>= 1) e += __shfl_xor(e, off);
        if (lane == 0) {
            float lt = cb0[(size_t)ccls * PLANE];
            loss += m + __logf(e) - lt;
        }
    }

    // block reduction -> partial store (no contended atomic)
    #pragma unroll
    for (int off = 32; off; off >>= 1) loss += __shfl_down(loss, off);
    if (lane == 0) s_red[wid] = loss;
    __syncthreads();
    float* partial = ws + PART_OFF;
    if (t == 0) {
        float s = 0.f;
        #pragma unroll
        for (int q = 0; q < BLOCK / 64; q++) s += s_red[q];
        partial[bid] = s;
        __threadfence();                       // publish partial (device scope)
        int old = atomicAdd((int*)ws + CNT_OFF, 1);
        s_last = (old == GRID - 1) ? 1 : 0;
    }
    __syncthreads();

    // last finished block performs the final reduction
    if (s_last) {
        __threadfence();                       // acquire: see all partials
        float s = 0.f;
        for (int i = t; i < GRID; i += BLOCK) s += partial[i];
        #pragma unroll
        for (int off = 32; off; off >>= 1) s += __shfl_down(s, off);
        if (lane == 0) s_red[wid] = s;
        __syncthreads();
        if (t == 0) {
            float tot = 0.f;
            #pragma unroll
            for (int q = 0; q < BLOCK / 64; q++) tot += s_red[q];
            d_out[0] = tot;
        }
    }
}

extern "C" void kernel_launch(void* const* d_in, const int* in_sizes, int n_in,
                              void* d_out, int out_size, void* d_ws, size_t ws_size,
                              hipStream_t stream) {
    const float* out = (const float*)d_in[0];
    const float* target = (const float*)d_in[1];
    float* ws = (float*)d_ws;
    float* o = (float*)d_out;

    hipLaunchKernelGGL(yolo_prep, dim3(NB), dim3(64), 0, stream, out, target, ws);
    hipLaunchKernelGGL(yolo_main, dim3(GRID), dim3(BLOCK), 0, stream, out, ws, o);
}

// Round 7
// 21.740 us; speedup vs baseline: 1.8304x; 1.8304x over previous
//
#include <hip/hip_runtime.h>

#define NB 16
#define NA 3
#define NC 80
#define NH 76
#define NW 76
#define MAX_GT 50
#define PLANE (NH * NW)       // 5776
#define CH (5 + NC)           // 85
#define IMG 608.0f
#define OBJSC 5.0f
#define BLOCK 256
#define CPB 512                              // cells per block (2 per thread)
#define BPP ((PLANE + CPB - 1) / CPB)        // 12
#define GRID (NB * NA * BPP)                 // 576
#define KSIL 0.375f                          // SIL/(1+SIL), SIL=0.6

__device__ __constant__ float c_aw[3] = {1.5f, 2.375f, 5.0f};
__device__ __constant__ float c_ah[3] = {2.0f, 4.5f, 3.5f};

__device__ inline float fast_sigmoid(float v) {
    return __builtin_amdgcn_rcpf(1.f + __expf(-v));
}

__device__ inline float iou_full(float x1, float y1, float w1, float h1,
                                 float x2, float y2, float w2, float h2) {
    float mx = fminf(x1 - w1 * 0.5f, x2 - w2 * 0.5f);
    float Mx = fmaxf(x1 + w1 * 0.5f, x2 + w2 * 0.5f);
    float my = fminf(y1 - h1 * 0.5f, y2 - h2 * 0.5f);
    float My = fmaxf(y1 + h1 * 0.5f, y2 + h2 * 0.5f);
    float cw = w1 + w2 - (Mx - mx);
    float ch = h1 + h2 - (My - my);
    float carea = (cw <= 0.f || ch <= 0.f) ? 0.f : cw * ch;
    float uarea = w1 * h1 + w2 * h2 - carea;
    return carea / uarea;
}

// Fused kernel (R5 skeleton): block = (b, a, 512-cell chunk). Wave 0 does the
// per-batch GT prep in LDS with Y-BAND CULLING+compaction for the silence loop;
// 256 threads each handle 2 cells (sharing GT reads); CE wave-cooperative;
// per-block partial -> ws (no contended atomic, no device fence).
__global__ __launch_bounds__(BLOCK) void yolo_fused(const float* __restrict__ out,
                                                    const float* __restrict__ target,
                                                    float* __restrict__ partial) {
    const int bid = blockIdx.x;
    const int plane_id = bid / BPP;
    const int cb = bid % BPP;
    const int b = plane_id / NA;
    const int a = plane_id % NA;
    const int t = threadIdx.x;
    const int cell0 = cb * CPB + t;
    const int cell1 = cell0 + BLOCK;
    const bool in0 = (cell0 < PLANE);
    const bool in1 = (cell1 < PLANE);
    const float jminf = (float)((cb * CPB) / NW);
    const float jmaxf = (float)((min(cb * CPB + CPB, PLANE) - 1) / NW);

    __shared__ float4 s_gtA[MAX_GT];          // culled: xlo, xhi, ylo, yhi
    __shared__ float4 s_gtB[MAX_GT];          // culled: gw, gh, KSIL*area, 0
    __shared__ float s_ent[MAX_GT][8];        // key, tx, ty, tw, th, tconf, cls, pad
    __shared__ int s_key[64];
    __shared__ int s_ovr[CPB];
    __shared__ int s_ce_cell[MAX_GT];
    __shared__ int s_ce_cls[MAX_GT];
    __shared__ int s_nv, s_cnt, s_nk, s_nce;
    __shared__ float s_red[BLOCK / 64];

    // ---- dense channel loads for both cells, issued first ----
    const float* base = out + ((size_t)(b * NA + a) * CH) * PLANE;
    float o00 = 0.f, o01 = 0.f, o02 = 0.f, o03 = 0.f, o04 = 0.f;
    float o10 = 0.f, o11 = 0.f, o12 = 0.f, o13 = 0.f, o14 = 0.f;
    if (in0) {
        o00 = base[cell0];
        o01 = base[cell0 + PLANE];
        o02 = base[cell0 + 2 * (size_t)PLANE];
        o03 = base[cell0 + 3 * (size_t)PLANE];
        o04 = base[cell0 + 4 * (size_t)PLANE];
    }
    if (in1) {
        o10 = base[cell1];
        o11 = base[cell1 + PLANE];
        o12 = base[cell1 + 2 * (size_t)PLANE];
        o13 = base[cell1 + 3 * (size_t)PLANE];
        o14 = base[cell1 + 4 * (size_t)PLANE];
    }

    s_ovr[t] = -1;
    s_ovr[t + BLOCK] = -1;
    if (t == 0) { s_cnt = 0; s_nce = 0; }

    // ---- prep: wave 0 only ----
    float e_tx = 0.f, e_ty = 0.f, e_tw = 0.f, e_th = 0.f, e_tc = 0.f, e_cls = 0.f;
    int key = -1;
    if (t < 64) {
        float pxr = 1.f;
        float xlo = 0.f, xhi = 0.f, ylo = 0.f, yhi = 0.f, gw = 0.f, gh = 0.f;
        if (t < MAX_GT) {
            const float* tg = target + (size_t)b * MAX_GT * 5 + t * 5;
            float gcls = tg[0];
            pxr = tg[1];
            float gx = tg[1] * (float)NW / IMG;
            float gy = tg[2] * (float)NH / IMG;
            gw = tg[3] * (float)NW / IMG;
            gh = tg[4] * (float)NH / IMG;
            xlo = gx - 0.5f * gw; xhi = gx + 0.5f * gw;
            ylo = gy - 0.5f * gh; yhi = gy + 0.5f * gh;

            // best anchor (first-max wins); boxes co-centered at 0
            int bn = 0; float best = -1.f;
            #pragma unroll
            for (int aa = 0; aa < NA; aa++) {
                float ca = fminf(gw, c_aw[aa]) * fminf(gh, c_ah[aa]);
                float ua = gw * gh + c_aw[aa] * c_ah[aa] - ca;
                float v = ca / ua;
                if (v > best) { best = v; bn = aa; }
            }
            int gi = (int)gx, gj = (int)gy;
            int gic = min(max(gi, 0), NW - 1), gjc = min(max(gj, 0), NH - 1);

            const float* pb = out + (((size_t)b * NA + bn) * CH) * PLANE
                              + (size_t)gjc * NW + gic;
            float q0 = pb[0];
            float q1 = pb[PLANE];
            float q2 = pb[2 * (size_t)PLANE];
            float q3 = pb[3 * (size_t)PLANE];
            float ppx = fast_sigmoid(q0) + (float)gic;
            float ppy = fast_sigmoid(q1) + (float)gjc;
            float ppw = __expf(q2) * c_aw[bn];
            float pph = __expf(q3) * c_ah[bn];
            float gx_c = 0.5f * (xlo + xhi), gy_c = 0.5f * (ylo + yhi);
            float iou = iou_full(gx_c, gy_c, gw, gh, ppx, ppy, ppw, pph);

            key = (gi >= 0 && gi < NW && gj >= 0 && gj < NH)
                      ? ((bn * NH + gj) * NW + gi) : -1;
            e_tx = gx_c - (float)gi;
            e_ty = gy_c - (float)gj;
            e_tw = __logf(gw / c_aw[bn]);
            e_th = __logf(gh / c_ah[bn]);
            e_tc = iou;
            e_cls = gcls;
        }
        s_key[t] = key;
        unsigned long long zm = __ballot((t < MAX_GT) && (pxr == 0.f));
        int nv = zm ? (int)(__ffsll((long long)zm) - 1) : MAX_GT;
        if (t == 0) s_nv = nv;

        // Y-band cull: GT can silence rows j in (ylo-0.234gh-1, yhi+0.234gh)
        // (derivation: IOU>0.6 => ph<gh/0.6 and intersection height >0.6gh).
        // Margin 0.25gh +/- 0.75 rows is conservatively wider.
        bool keep = (t < nv) &&
                    (jmaxf + 0.75f > ylo - 0.25f * gh - 1.0f) &&
                    (jminf - 0.75f < yhi + 0.25f * gh);
        unsigned long long km = __ballot(keep);
        if (keep) {
            int pos = (int)__popcll(km & ((1ull << t) - 1ull));
            s_gtA[pos] = make_float4(xlo, xhi, ylo, yhi);
            s_gtB[pos] = make_float4(gw, gh, KSIL * gw * gh, 0.f);
        }
        if (t == 0) s_nk = (int)__popcll(km);
    }
    __syncthreads();

    // ---- dedup (last-write-wins) + compaction: wave 0 ----
    if (t < 64) {
        int nv = s_nv;
        bool winner = (t < nv) && (key >= 0);
        if (winner) {
            for (int u = t + 1; u < nv; u++)
                if (s_key[u] == key) { winner = false; break; }
        }
        if (winner) {
            int slot = atomicAdd(&s_cnt, 1);
            s_ent[slot][0] = (float)key;   // < 2^24, exact
            s_ent[slot][1] = e_tx;
            s_ent[slot][2] = e_ty;
            s_ent[slot][3] = e_tw;
            s_ent[slot][4] = e_th;
            s_ent[slot][5] = e_tc;
            s_ent[slot][6] = e_cls;
            s_ent[slot][7] = 0.f;
        }
    }
    __syncthreads();

    // ---- scatter entries into this block's per-cell override map ----
    if (t < s_cnt) {
        int k = (int)s_ent[t][0];
        int ae = k / PLANE;
        int local = (k - ae * PLANE) - cb * CPB;
        if (ae == a && local >= 0 && local < CPB) s_ovr[local] = t;
    }
    __syncthreads();

    // ---- dense per-cell loss, 2 cells/thread sharing GT reads ----
    float x0 = fast_sigmoid(o00), y0 = fast_sigmoid(o01), cf0 = fast_sigmoid(o04);
    float pw0 = __expf(o02) * c_aw[a], ph0 = __expf(o03) * c_ah[a];
    int j0 = cell0 / NW, i0 = cell0 - j0 * NW;
    float px0 = x0 + (float)i0, py0 = y0 + (float)j0;
    float xl0 = px0 - 0.5f * pw0, xh0 = px0 + 0.5f * pw0;
    float yl0 = py0 - 0.5f * ph0, yh0 = py0 + 0.5f * ph0;
    float kpa0 = KSIL * pw0 * ph0;

    float x1 = fast_sigmoid(o10), y1 = fast_sigmoid(o11), cf1 = fast_sigmoid(o14);
    float pw1 = __expf(o12) * c_aw[a], ph1 = __expf(o13) * c_ah[a];
    int j1 = cell1 / NW, i1 = cell1 - j1 * NW;
    float px1 = x1 + (float)i1, py1 = y1 + (float)j1;
    float xl1 = px1 - 0.5f * pw1, xh1 = px1 + 0.5f * pw1;
    float yl1 = py1 - 0.5f * ph1, yh1 = py1 + 0.5f * ph1;
    float kpa1 = KSIL * pw1 * ph1;

    bool sil0 = false, sil1 = false;
    int nk = s_nk;
    for (int tt = 0; tt < nk; tt++) {
        float4 gA = s_gtA[tt];
        float4 gB = s_gtB[tt];
        {
            float mx = fminf(xl0, gA.x), Mx = fmaxf(xh0, gA.y);
            float my = fminf(yl0, gA.z), My = fmaxf(yh0, gA.w);
            float cw = (pw0 + gB.x) - (Mx - mx);
            float ch = (ph0 + gB.y) - (My - my);
            sil0 |= (fminf(cw, ch) > 0.f) & (cw * ch > kpa0 + gB.z);
        }
        {
            float mx = fminf(xl1, gA.x), Mx = fmaxf(xh1, gA.y);
            float my = fminf(yl1, gA.z), My = fmaxf(yh1, gA.w);
            float cw = (pw1 + gB.x) - (Mx - mx);
            float ch = (ph1 + gB.y) - (My - my);
            sil1 |= (fminf(cw, ch) > 0.f) & (cw * ch > kpa1 + gB.z);
        }
    }

    float loss = 0.f;
    if (in0) {
        float cm = sil0 ? 0.f : 1.f;   // NOOBJ_SCALE = 1
        float tx = 0.5f, ty = 0.5f, tw = 0.f, th = 0.f, tc = 0.f;
        int ov = s_ovr[t];
        if (ov >= 0) {
            tx = s_ent[ov][1]; ty = s_ent[ov][2]; tw = s_ent[ov][3];
            th = s_ent[ov][4]; tc = s_ent[ov][5];
            cm = OBJSC;
            int idx = atomicAdd(&s_nce, 1);
            s_ce_cell[idx] = cell0;
            s_ce_cls[idx] = (int)s_ent[ov][6];
        }
        float dx = x0 - tx, dy = y0 - ty, dw = o02 - tw, dh = o03 - th, dc = cf0 - tc;
        loss += 0.5f * (dx * dx + dy * dy + dw * dw + dh * dh + cm * dc * dc);
    }
    if (in1) {
        float cm = sil1 ? 0.f : 1.f;
        float tx = 0.5f, ty = 0.5f, tw = 0.f, th = 0.f, tc = 0.f;
        int ov = s_ovr[t + BLOCK];
        if (ov >= 0) {
            tx = s_ent[ov][1]; ty = s_ent[ov][2]; tw = s_ent[ov][3];
            th = s_ent[ov][4]; tc = s_ent[ov][5];
            cm = OBJSC;
            int idx = atomicAdd(&s_nce, 1);
            s_ce_cell[idx] = cell1;
            s_ce_cls[idx] = (int)s_ent[ov][6];
        }
        float dx = x1 - tx, dy = y1 - ty, dw = o12 - tw, dh = o13 - th, dc = cf1 - tc;
        loss += 0.5f * (dx * dx + dy * dy + dw * dw + dh * dh + cm * dc * dc);
    }
    __syncthreads();

    // ---- wave-cooperative CE for this block's GT cells ----
    int nce = s_nce;
    int wid = t >> 6, lane = t & 63;
    for (int k = wid; k < nce; k += BLOCK / 64) {
        int ccell = s_ce_cell[k];
        int ccls = s_ce_cls[k];
        const float* cb0 = base + 5 * (size_t)PLANE + ccell;
        float v1 = cb0[(size_t)lane * PLANE];
        float v2 = (lane < NC - 64) ? cb0[(size_t)(lane + 64) * PLANE] : -3.4e38f;
        float m = fmaxf(v1, v2);
        #pragma unroll
        for (int off = 32; off; off >>= 1) m = fmaxf(m, __shfl_xor(m, off));
        float e = __expf(v1 - m) + ((lane < NC - 64) ? __expf(v2 - m) : 0.f);
        #pragma unroll
        for (int off = 32; off; off >>= 1) e += __shfl_xor(e, off);
        if (lane == 0) {
            float lt = cb0[(size_t)ccls * PLANE];
            loss += m + __logf(e) - lt;
        }
    }

    // ---- block reduction -> partial store ----
    #pragma unroll
    for (int off = 32; off; off >>= 1) loss += __shfl_down(loss, off);
    if (lane == 0) s_red[wid] = loss;
    __syncthreads();
    if (t == 0) {
        float s = 0.f;
        #pragma unroll
        for (int q = 0; q < BLOCK / 64; q++) s += s_red[q];
        partial[bid] = s;
    }
}

// Final reduction: one block sums the 576 per-block partials.
__global__ __launch_bounds__(BLOCK) void yolo_reduce(const float* __restrict__ partial,
                                                     float* __restrict__ d_out) {
    int t = threadIdx.x;
    __shared__ float s_red[BLOCK / 64];
    float s = 0.f;
    for (int i = t; i < GRID; i += BLOCK) s += partial[i];
    #pragma unroll
    for (int off = 32; off; off >>= 1) s += __shfl_down(s, off);
    if ((t & 63) == 0) s_red[t >> 6] = s;
    __syncthreads();
    if (t == 0) {
        float tot = 0.f;
        #pragma unroll
        for (int q = 0; q < BLOCK / 64; q++) tot += s_red[q];
        d_out[0] = tot;
    }
}

extern "C" void kernel_launch(void* const* d_in, const int* in_sizes, int n_in,
                              void* d_out, int out_size, void* d_ws, size_t ws_size,
                              hipStream_t stream) {
    const float* out = (const float*)d_in[0];
    const float* target = (const float*)d_in[1];
    float* partial = (float*)d_ws;
    float* o = (float*)d_out;

    hipLaunchKernelGGL(yolo_fused, dim3(GRID), dim3(BLOCK), 0, stream,
                       out, target, partial);
    hipLaunchKernelGGL(yolo_reduce, dim3(1), dim3(BLOCK), 0, stream,
                       partial, o);
}

// Round 8
// 17.160 us; speedup vs baseline: 2.3189x; 1.2669x over previous
//
#include <hip/hip_runtime.h>

#define NB 16
#define NA 3
#define NC 80
#define NH 76
#define NW 76
#define MAX_GT 50
#define PLANE (NH * NW)       // 5776
#define CH (5 + NC)           // 85
#define IMG 608.0f
#define OBJSC 5.0f
#define BLOCK 256
#define CPB 512                              // cells per block (2 adjacent per thread)
#define BPP ((PLANE + CPB - 1) / CPB)        // 12
#define GRID (NB * NA * BPP)                 // 576
#define KSIL 0.375f                          // SIL/(1+SIL), SIL=0.6

__device__ __constant__ float c_aw[3] = {1.5f, 2.375f, 5.0f};
__device__ __constant__ float c_ah[3] = {2.0f, 4.5f, 3.5f};

__device__ inline float fast_sigmoid(float v) {
    return __builtin_amdgcn_rcpf(1.f + __expf(-v));
}

__device__ inline float iou_full(float x1, float y1, float w1, float h1,
                                 float x2, float y2, float w2, float h2) {
    float mx = fminf(x1 - w1 * 0.5f, x2 - w2 * 0.5f);
    float Mx = fmaxf(x1 + w1 * 0.5f, x2 + w2 * 0.5f);
    float my = fminf(y1 - h1 * 0.5f, y2 - h2 * 0.5f);
    float My = fmaxf(y1 + h1 * 0.5f, y2 + h2 * 0.5f);
    float cw = w1 + w2 - (Mx - mx);
    float ch = h1 + h2 - (My - my);
    float carea = (cw <= 0.f || ch <= 0.f) ? 0.f : cw * ch;
    float uarea = w1 * h1 + w2 * h2 - carea;
    return carea / uarea;
}

// Fused kernel: block = (b, a, 512-cell chunk), 2 adjacent cells/thread
// (float2 loads). Wave 0 prep; last-write-wins via LDS atomicMax (no dedup
// phase); CE list built early and first entry per wave PREFETCHED so its
// gathered loads hide under the dense phase. Per-block partial -> ws.
__global__ __launch_bounds__(BLOCK) void yolo_fused(const float* __restrict__ out,
                                                    const float* __restrict__ target,
                                                    float* __restrict__ partial) {
    const int bid = blockIdx.x;
    const int plane_id = bid / BPP;
    const int cb = bid % BPP;
    const int b = plane_id / NA;
    const int a = plane_id % NA;
    const int t = threadIdx.x;
    const int cell0 = cb * CPB + 2 * t;      // even; pair never straddles PLANE
    const int cell1 = cell0 + 1;
    const bool valid = (cell0 < PLANE);
    const float jminf = (float)((cb * CPB) / NW);
    const float jmaxf = (float)((min(cb * CPB + CPB, PLANE) - 1) / NW);

    __shared__ float4 s_gtA[MAX_GT];          // culled: xlo, xhi, ylo, yhi
    __shared__ float4 s_gtB[MAX_GT];          // culled: gw, gh, KSIL*area, 0
    __shared__ float s_ent[MAX_GT][8];        // per-GT: -, tx, ty, tw, th, tconf, cls, -
    __shared__ int s_ovr[CPB];                // local cell -> GT index (atomicMax)
    __shared__ int s_ce_cell[MAX_GT];
    __shared__ int s_ce_ov[MAX_GT];
    __shared__ int s_nv, s_nk, s_nce;
    __shared__ float s_red[BLOCK / 64];

    // ---- dense channel loads: float2 per channel, issued first ----
    const float* base = out + ((size_t)(b * NA + a) * CH) * PLANE;
    float2 v0 = {0.f, 0.f}, v1c = {0.f, 0.f}, v2c = {0.f, 0.f},
           v3c = {0.f, 0.f}, v4c = {0.f, 0.f};
    if (valid) {
        v0  = *(const float2*)&base[cell0];
        v1c = *(const float2*)&base[cell0 + PLANE];
        v2c = *(const float2*)&base[cell0 + 2 * (size_t)PLANE];
        v3c = *(const float2*)&base[cell0 + 3 * (size_t)PLANE];
        v4c = *(const float2*)&base[cell0 + 4 * (size_t)PLANE];
    }

    s_ovr[t] = -1;
    s_ovr[t + BLOCK] = -1;
    if (t == 0) s_nce = 0;

    // ---- prep: wave 0 only (no dedup phase) ----
    int key = -1;
    if (t < 64) {
        float pxr = 1.f;
        float xlo = 0.f, xhi = 0.f, ylo = 0.f, yhi = 0.f, gw = 0.f, gh = 0.f;
        if (t < MAX_GT) {
            const float* tg = target + (size_t)b * MAX_GT * 5 + t * 5;
            float gcls = tg[0];
            pxr = tg[1];
            float gx = tg[1] * (float)NW / IMG;
            float gy = tg[2] * (float)NH / IMG;
            gw = tg[3] * (float)NW / IMG;
            gh = tg[4] * (float)NH / IMG;
            xlo = gx - 0.5f * gw; xhi = gx + 0.5f * gw;
            ylo = gy - 0.5f * gh; yhi = gy + 0.5f * gh;

            // best anchor (first-max wins); boxes co-centered at 0
            int bn = 0; float best = -1.f;
            #pragma unroll
            for (int aa = 0; aa < NA; aa++) {
                float ca = fminf(gw, c_aw[aa]) * fminf(gh, c_ah[aa]);
                float ua = gw * gh + c_aw[aa] * c_ah[aa] - ca;
                float v = ca / ua;
                if (v > best) { best = v; bn = aa; }
            }
            int gi = (int)gx, gj = (int)gy;
            int gic = min(max(gi, 0), NW - 1), gjc = min(max(gj, 0), NH - 1);

            const float* pb = out + (((size_t)b * NA + bn) * CH) * PLANE
                              + (size_t)gjc * NW + gic;
            float q0 = pb[0];
            float q1 = pb[PLANE];
            float q2 = pb[2 * (size_t)PLANE];
            float q3 = pb[3 * (size_t)PLANE];
            float ppx = fast_sigmoid(q0) + (float)gic;
            float ppy = fast_sigmoid(q1) + (float)gjc;
            float ppw = __expf(q2) * c_aw[bn];
            float pph = __expf(q3) * c_ah[bn];
            float iou = iou_full(gx, gy, gw, gh, ppx, ppy, ppw, pph);

            key = (gi >= 0 && gi < NW && gj >= 0 && gj < NH)
                      ? ((bn * NH + gj) * NW + gi) : -1;
            s_ent[t][1] = gx - (float)gi;
            s_ent[t][2] = gy - (float)gj;
            s_ent[t][3] = __logf(gw / c_aw[bn]);
            s_ent[t][4] = __logf(gh / c_ah[bn]);
            s_ent[t][5] = iou;
            s_ent[t][6] = gcls;
        }
        unsigned long long zm = __ballot((t < MAX_GT) && (pxr == 0.f));
        int nv = zm ? (int)(__ffsll((long long)zm) - 1) : MAX_GT;
        if (t == 0) s_nv = nv;

        // Y-band cull for the silence loop (conservative; see R7 derivation)
        bool keep = (t < nv) &&
                    (jmaxf + 0.75f > ylo - 0.25f * gh - 1.0f) &&
                    (jminf - 0.75f < yhi + 0.25f * gh);
        unsigned long long km = __ballot(keep);
        if (keep) {
            int pos = (int)__popcll(km & ((1ull << t) - 1ull));
            s_gtA[pos] = make_float4(xlo, xhi, ylo, yhi);
            s_gtB[pos] = make_float4(gw, gh, KSIL * gw * gh, 0.f);
        }
        if (t == 0) s_nk = (int)__popcll(km);
    }
    __syncthreads();

    // ---- scatter: last-write-wins = highest GT index via atomicMax ----
    if (t < s_nv && key >= 0) {
        int ae = key / PLANE;
        int local = (key - ae * PLANE) - cb * CPB;
        if (ae == a && local >= 0 && local < CPB) atomicMax(&s_ovr[local], t);
    }
    __syncthreads();

    // ---- build CE list from this thread's two cells ----
    int ovA = valid ? s_ovr[2 * t] : -1;
    int ovB = valid ? s_ovr[2 * t + 1] : -1;
    if (ovA >= 0) {
        int idx = atomicAdd(&s_nce, 1);
        s_ce_cell[idx] = cell0; s_ce_ov[idx] = ovA;
    }
    if (ovB >= 0) {
        int idx = atomicAdd(&s_nce, 1);
        s_ce_cell[idx] = cell1; s_ce_ov[idx] = ovB;
    }
    __syncthreads();

    const int nce = s_nce;
    const int wid = t >> 6, lane = t & 63;
    const float* cls_base = base + 5 * (size_t)PLANE;

    // ---- CE prefetch: first entry per wave, loads issue BEFORE dense ----
    float ce1 = 0.f, ce2 = -3.4e38f, celt = 0.f;
    const bool havece = (wid < nce);
    if (havece) {
        int ccell = s_ce_cell[wid];
        int ccls = (int)s_ent[s_ce_ov[wid]][6];
        const float* cb0 = cls_base + ccell;
        ce1 = cb0[(size_t)lane * PLANE];
        if (lane < NC - 64) ce2 = cb0[(size_t)(lane + 64) * PLANE];
        celt = cb0[(size_t)ccls * PLANE];
    }

    // ---- dense loss for both cells ----
    float loss = 0.f;
    if (valid) {
        int j0 = cell0 / NW, i0 = cell0 - j0 * NW;
        int j1 = cell1 / NW, i1 = cell1 - j1 * NW;

        float x0 = fast_sigmoid(v0.x), y0 = fast_sigmoid(v1c.x), cf0 = fast_sigmoid(v4c.x);
        float pw0 = __expf(v2c.x) * c_aw[a], ph0 = __expf(v3c.x) * c_ah[a];
        float px0 = x0 + (float)i0, py0 = y0 + (float)j0;
        float xl0 = px0 - 0.5f * pw0, xh0 = px0 + 0.5f * pw0;
        float yl0 = py0 - 0.5f * ph0, yh0 = py0 + 0.5f * ph0;
        float kpa0 = KSIL * pw0 * ph0;

        float x1 = fast_sigmoid(v0.y), y1 = fast_sigmoid(v1c.y), cf1 = fast_sigmoid(v4c.y);
        float pw1 = __expf(v2c.y) * c_aw[a], ph1 = __expf(v3c.y) * c_ah[a];
        float px1 = x1 + (float)i1, py1 = y1 + (float)j1;
        float xl1 = px1 - 0.5f * pw1, xh1 = px1 + 0.5f * pw1;
        float yl1 = py1 - 0.5f * ph1, yh1 = py1 + 0.5f * ph1;
        float kpa1 = KSIL * pw1 * ph1;

        bool sil0 = false, sil1 = false;
        int nk = s_nk;
        for (int tt = 0; tt < nk; tt++) {
            float4 gA = s_gtA[tt];
            float4 gB = s_gtB[tt];
            {
                float mx = fminf(xl0, gA.x), Mx = fmaxf(xh0, gA.y);
                float my = fminf(yl0, gA.z), My = fmaxf(yh0, gA.w);
                float cw = (pw0 + gB.x) - (Mx - mx);
                float ch = (ph0 + gB.y) - (My - my);
                sil0 |= (fminf(cw, ch) > 0.f) & (cw * ch > kpa0 + gB.z);
            }
            {
                float mx = fminf(xl1, gA.x), Mx = fmaxf(xh1, gA.y);
                float my = fminf(yl1, gA.z), My = fmaxf(yh1, gA.w);
                float cw = (pw1 + gB.x) - (Mx - mx);
                float ch = (ph1 + gB.y) - (My - my);
                sil1 |= (fminf(cw, ch) > 0.f) & (cw * ch > kpa1 + gB.z);
            }
        }

        {
            float cm = sil0 ? 0.f : 1.f;   // NOOBJ_SCALE = 1
            float tx = 0.5f, ty = 0.5f, tw = 0.f, th = 0.f, tc = 0.f;
            if (ovA >= 0) {
                tx = s_ent[ovA][1]; ty = s_ent[ovA][2]; tw = s_ent[ovA][3];
                th = s_ent[ovA][4]; tc = s_ent[ovA][5];
                cm = OBJSC;
            }
            float dx = x0 - tx, dy = y0 - ty, dw = v2c.x - tw, dh = v3c.x - th, dc = cf0 - tc;
            loss += 0.5f * (dx * dx + dy * dy + dw * dw + dh * dh + cm * dc * dc);
        }
        {
            float cm = sil1 ? 0.f : 1.f;
            float tx = 0.5f, ty = 0.5f, tw = 0.f, th = 0.f, tc = 0.f;
            if (ovB >= 0) {
                tx = s_ent[ovB][1]; ty = s_ent[ovB][2]; tw = s_ent[ovB][3];
                th = s_ent[ovB][4]; tc = s_ent[ovB][5];
                cm = OBJSC;
            }
            float dx = x1 - tx, dy = y1 - ty, dw = v2c.y - tw, dh = v3c.y - th, dc = cf1 - tc;
            loss += 0.5f * (dx * dx + dy * dy + dw * dw + dh * dh + cm * dc * dc);
        }
    }

    // ---- CE finish (prefetched entry) ----
    if (havece) {
        float m = fmaxf(ce1, ce2);
        #pragma unroll
        for (int off = 32; off; off >>= 1) m = fmaxf(m, __shfl_xor(m, off));
        float e = __expf(ce1 - m) + ((lane < NC - 64) ? __expf(ce2 - m) : 0.f);
        #pragma unroll
        for (int off = 32; off; off >>= 1) e += __shfl_xor(e, off);
        if (lane == 0) loss += m + __logf(e) - celt;
    }
    // leftover CE entries (rare: >4 GT cells in one chunk)
    for (int k = wid + 4; k < nce; k += 4) {
        int ccell = s_ce_cell[k];
        int ccls = (int)s_ent[s_ce_ov[k]][6];
        const float* cb0 = cls_base + ccell;
        float w1 = cb0[(size_t)lane * PLANE];
        float w2 = (lane < NC - 64) ? cb0[(size_t)(lane + 64) * PLANE] : -3.4e38f;
        float m = fmaxf(w1, w2);
        #pragma unroll
        for (int off = 32; off; off >>= 1) m = fmaxf(m, __shfl_xor(m, off));
        float e = __expf(w1 - m) + ((lane < NC - 64) ? __expf(w2 - m) : 0.f);
        #pragma unroll
        for (int off = 32; off; off >>= 1) e += __shfl_xor(e, off);
        if (lane == 0) loss += m + __logf(e) - cb0[(size_t)ccls * PLANE];
    }

    // ---- block reduction -> partial store ----
    #pragma unroll
    for (int off = 32; off; off >>= 1) loss += __shfl_down(loss, off);
    if (lane == 0) s_red[wid] = loss;
    __syncthreads();
    if (t == 0) {
        float s = 0.f;
        #pragma unroll
        for (int q = 0; q < BLOCK / 64; q++) s += s_red[q];
        partial[bid] = s;
    }
}

// Final reduction: one block sums the 576 per-block partials.
__global__ __launch_bounds__(BLOCK) void yolo_reduce(const float* __restrict__ partial,
                                                     float* __restrict__ d_out) {
    int t = threadIdx.x;
    __shared__ float s_red[BLOCK / 64];
    float s = 0.f;
    for (int i = t; i < GRID; i += BLOCK) s += partial[i];
    #pragma unroll
    for (int off = 32; off; off >>= 1) s += __shfl_down(s, off);
    if ((t & 63) == 0) s_red[t >> 6] = s;
    __syncthreads();
    if (t == 0) {
        float tot = 0.f;
        #pragma unroll
        for (int q = 0; q < BLOCK / 64; q++) tot += s_red[q];
        d_out[0] = tot;
    }
}

extern "C" void kernel_launch(void* const* d_in, const int* in_sizes, int n_in,
                              void* d_out, int out_size, void* d_ws, size_t ws_size,
                              hipStream_t stream) {
    const float* out = (const float*)d_in[0];
    const float* target = (const float*)d_in[1];
    float* partial = (float*)d_ws;
    float* o = (float*)d_out;

    hipLaunchKernelGGL(yolo_fused, dim3(GRID), dim3(BLOCK), 0, stream,
                       out, target, partial);
    hipLaunchKernelGGL(yolo_reduce, dim3(1), dim3(BLOCK), 0, stream,
                       partial, o);
}